// Round 17
// baseline (84.289 us; speedup 1.0000x reference)
//
#include <hip/hip_runtime.h>
#include <hip/hip_bf16.h>
#include <math.h>

// GAT: B=4, N=2048, in=128, out=32, heads=4
// outputs: H_new [4,2048,128] f32 (1048576) then alpha [4,4,2048,2048] f32 (67108864)

typedef float f32x4 __attribute__((ext_vector_type(4)));
typedef short bf16x8 __attribute__((ext_vector_type(8)));
typedef unsigned int u32;

#define LRELU 0.2f
#define LOG2E 1.44269504088896f
#define EXP2(x) __builtin_amdgcn_exp2f(x)

__device__ inline ushort f2b(float x) {
    unsigned int u = __float_as_uint(x);
    u += 0x7fffu + ((u >> 16) & 1u);   // RNE
    return (ushort)(u >> 16);
}

// ---------------- kA: Ht^T = W^T @ H^T (MFMA), + src/dst dots ------------------------------
// grid (32 ntiles, 16 bh), block 256.
__global__ __launch_bounds__(256) void kA_ht(const float* __restrict__ H,
                                             const float* __restrict__ W,
                                             const float* __restrict__ a,
                                             __hip_bfloat16* __restrict__ HtT,
                                             float* __restrict__ src,
                                             float* __restrict__ dst) {
    __shared__ __align__(16) ushort Wbf[32 * 128];   // W bf16 swizzled; reused as T

    int t = threadIdx.x;
    int ntile = blockIdx.x;
    int bh = blockIdx.y;
    int b = bh >> 2, h = bh & 3;
    int lane = t & 63, w = t >> 6;
    int l15 = lane & 15, l4 = lane >> 4;

    #pragma unroll
    for (int u = 0; u < 16; ++u) {
        int idx = u * 256 + t;
        int i = idx >> 5, f = idx & 31;
        Wbf[(f * 128 + i) ^ ((f & 7) << 3)] = f2b(W[h * 4096 + idx]);
    }
    __syncthreads();

    int n = ntile * 64 + w * 16 + l15;
    const float* hrow = H + ((size_t)(b * 2048) + n) * 128;

    f32x4 acc0 = {0.f, 0.f, 0.f, 0.f};   // f rows 0-15
    f32x4 acc1 = {0.f, 0.f, 0.f, 0.f};   // f rows 16-31
    #pragma unroll
    for (int kc = 0; kc < 4; ++kc) {
        int k0 = kc * 32 + l4 * 8;
        float4 h0 = *(const float4*)(hrow + k0);
        float4 h1 = *(const float4*)(hrow + k0 + 4);
        union { u32 u[4]; bf16x8 v; } bu;
        asm("v_cvt_pk_bf16_f32 %0, %1, %2" : "=v"(bu.u[0]) : "v"(h0.x), "v"(h0.y));
        asm("v_cvt_pk_bf16_f32 %0, %1, %2" : "=v"(bu.u[1]) : "v"(h0.z), "v"(h0.w));
        asm("v_cvt_pk_bf16_f32 %0, %1, %2" : "=v"(bu.u[2]) : "v"(h1.x), "v"(h1.y));
        asm("v_cvt_pk_bf16_f32 %0, %1, %2" : "=v"(bu.u[3]) : "v"(h1.z), "v"(h1.w));
        bf16x8 bfrag = bu.v;
        bf16x8 af0 = *(const bf16x8*)&Wbf[(l15 * 128 + kc * 32 + l4 * 8) ^ ((l15 & 7) << 3)];
        bf16x8 af1 = *(const bf16x8*)&Wbf[((16 + l15) * 128 + kc * 32 + l4 * 8) ^ (((16 + l15) & 7) << 3)];
        acc0 = __builtin_amdgcn_mfma_f32_16x16x32_bf16(af0, bfrag, acc0, 0, 0, 0);
        acc1 = __builtin_amdgcn_mfma_f32_16x16x32_bf16(af1, bfrag, acc1, 0, 0, 0);
    }

    float sv = 0.f, dvv = 0.f;
    #pragma unroll
    for (int r = 0; r < 4; ++r) {
        int f0 = l4 * 4 + r;
        sv  += acc0[r] * a[h * 64 + f0]      + acc1[r] * a[h * 64 + 16 + f0];
        dvv += acc0[r] * a[h * 64 + 32 + f0] + acc1[r] * a[h * 64 + 48 + f0];
    }
    sv  += __shfl_xor(sv, 16);  sv  += __shfl_xor(sv, 32);
    dvv += __shfl_xor(dvv, 16); dvv += __shfl_xor(dvv, 32);
    if (l4 == 0) { src[bh * 2048 + n] = sv; dst[bh * 2048 + n] = dvv; }

    // HtT via LDS transpose (reuse Wbf as T[32 f][64 n]) for coalesced 16B stores
    __syncthreads();
    ushort* T = Wbf;
    int nl = w * 16 + l15;
    #pragma unroll
    for (int r = 0; r < 4; ++r) {
        int f0 = l4 * 4 + r;
        T[f0 * 64 + nl]        = f2b(acc0[r]);
        T[(16 + f0) * 64 + nl] = f2b(acc1[r]);
    }
    __syncthreads();
    {
        int f = t >> 3, n8 = (t & 7) * 8;
        uint4 v = *(const uint4*)&T[f * 64 + n8];
        *(uint4*)((ushort*)HtT + (size_t)(bh * 32 + f) * 2048 + ntile * 64 + n8) = v;
    }
}

// ---------------- k0S: pack adjI AND compute rowL for all 16 bh ---------------------------
// grid 1024 blocks x 2 rows, block 256 (4 waves). Wave w handles bh {w, w+4, w+8, w+12}.
// Pass A's exp2 work runs here, overlapped with the adj->adjI streaming, so k2's waves hit
// the alpha store path immediately.
__global__ __launch_bounds__(256) void k0S(const float* __restrict__ adj,
                                           const float* __restrict__ src,
                                           const float* __restrict__ dst,
                                           unsigned char* __restrict__ adjI,
                                           float* __restrict__ rowLG) {
    __shared__ __align__(16) unsigned char aS[2 * 2048];   // 4 KB

    int t = threadIdx.x;
    int row0 = blockIdx.x * 2;
    int lane = t & 63, w = t >> 6;

    // stage 2 adj rows -> pack adjI (global + LDS)
    #pragma unroll
    for (int u = 0; u < 4; ++u) {
        int s = u * 256 + t;
        int e0 = s * 4;
        int r = e0 >> 11, c = e0 & 2047;
        float4 v = *(const float4*)(adj + (size_t)(row0 + r) * 2048 + c);
        uchar4 o;
        o.x = (v.x != 0.f || c     == row0 + r) ? 1 : 0;
        o.y = (v.y != 0.f || c + 1 == row0 + r) ? 1 : 0;
        o.z = (v.z != 0.f || c + 2 == row0 + r) ? 1 : 0;
        o.w = (v.w != 0.f || c + 3 == row0 + r) ? 1 : 0;
        *(uchar4*)(adjI + (size_t)(row0 + r) * 2048 + c) = o;
        *(uchar4*)&aS[r * 2048 + c] = o;
    }
    __syncthreads();

    const u32* aSu = (const u32*)aS;
    #pragma unroll
    for (int i = 0; i < 4; ++i) {
        int bh = w + i * 4;
        float4 dv[8];
        #pragma unroll
        for (int j = 0; j < 8; ++j) {
            float4 v = *(const float4*)(dst + (size_t)bh * 2048 + j * 256 + lane * 4);
            v.x *= LOG2E; v.y *= LOG2E; v.z *= LOG2E; v.w *= LOG2E;
            dv[j] = v;
        }
        #pragma unroll
        for (int r = 0; r < 2; ++r) {
            float sn = src[bh * 2048 + row0 + r] * LOG2E;
            float S = 0.f;
            #pragma unroll
            for (int j = 0; j < 8; ++j) {
                u32 ab = aSu[r * 512 + j * 64 + lane];
                float dj[4] = {dv[j].x, dv[j].y, dv[j].z, dv[j].w};
                #pragma unroll
                for (int q = 0; q < 4; ++q) {
                    float ajf = (float)((ab >> (8 * q)) & 0xffu);
                    float ee = sn + dj[q];
                    float vm = fmaxf(ee, LRELU * ee);
                    S = fmaf(EXP2(vm), ajf, S);
                }
            }
            #pragma unroll
            for (int off = 32; off; off >>= 1) S += __shfl_xor(S, off);
            if (lane == 0) rowLG[bh * 2048 + row0 + r] = -__log2f(S);
        }
    }
}

// ---------------- k2: pass B only — softmax -> alpha (store) -> MFMA -> ELU -> H_new -------
// grid (64 mtiles of 32 rows, 16 bh), block 256 (4 waves). 4 blocks/CU (VGPR cap 128).
// As double-buffered: ONE lgkm-only barrier per K-chunk; loads always issued before stores.
__global__ __launch_bounds__(256, 4) void k2_fused(const unsigned char* __restrict__ adjI,
                                                   const float* __restrict__ src,
                                                   const float* __restrict__ dst,
                                                   const float* __restrict__ rowLG,
                                                   const __hip_bfloat16* __restrict__ HtT,
                                                   float* __restrict__ alpha,
                                                   float* __restrict__ outH) {
    __shared__ float dstS[2048];                      // 8 KB (pre-scaled by LOG2E)
    __shared__ float rowL[32], rowSrcS[32];
    __shared__ __align__(16) ushort As[2][32 * 128];  // 16 KB dbuf, XOR-swizzled

    int t = threadIdx.x;
    int mtile = blockIdx.x;   // 64
    int bh    = blockIdx.y;   // 16
    int lane = t & 63, w = t >> 6;
    int b = bh >> 2, h = bh & 3;
    int row0 = mtile * 32;

    const float4* dst4g = (const float4*)(dst + bh * 2048);
    #pragma unroll
    for (int u = 0; u < 2; ++u) {
        float4 v = dst4g[u * 256 + t];
        v.x *= LOG2E; v.y *= LOG2E; v.z *= LOG2E; v.w *= LOG2E;
        *(float4*)&dstS[(u * 256 + t) * 4] = v;
    }
    if (t < 32) {
        rowSrcS[t] = src[bh * 2048 + row0 + t] * LOG2E;
        rowL[t]    = rowLG[bh * 2048 + row0 + t];
    }
    __syncthreads();

    f32x4 acc = {0.f, 0.f, 0.f, 0.f};
    int wr = w >> 1, wc = w & 1;
    int l15 = lane & 15, l4 = lane >> 4;
    int arow = wr * 16 + l15;
    const ushort* Bfp = (const ushort*)HtT + (size_t)(bh * 32 + wc * 16 + l15) * 2048 + l4 * 8;
    float* alphaRow = alpha + (size_t)(bh * 2048 + row0) * 2048;

    int sr = t >> 5;            // rows sr, sr+8, sr+16, sr+24
    int sc4 = t & 31;

    float snR[4], LR[4];
    #pragma unroll
    for (int u = 0; u < 4; ++u) { snR[u] = rowSrcS[sr + u * 8]; LR[u] = rowL[sr + u * 8]; }

    auto loadA = [&](int k, u32* ar) {
        #pragma unroll
        for (int u = 0; u < 4; ++u)
            ar[u] = *(const u32*)(adjI + (size_t)(row0 + sr + u * 8) * 2048 + k * 128 + sc4 * 4);
    };
    auto loadB = [&](int k, bf16x8* br) {
        #pragma unroll
        for (int kk = 0; kk < 4; ++kk)
            br[kk] = *(const bf16x8*)(Bfp + (size_t)k * 128 + kk * 32);
    };
    auto stage = [&](int k, const u32* ar, ushort* Asb) {
        int jb = k * 128 + sc4 * 4;
        float4 dv = *(const float4*)&dstS[jb];
        float dj[4] = {dv.x, dv.y, dv.z, dv.w};
        #pragma unroll
        for (int u = 0; u < 4; ++u) {
            int r = sr + u * 8;
            float sn = snR[u], L = LR[u];
            u32 ab = ar[u];
            float o[4];
            #pragma unroll
            for (int q = 0; q < 4; ++q) {
                float ajf = (float)((ab >> (8 * q)) & 0xffu);
                float ee = sn + dj[q];
                float vm = fmaxf(ee + L, fmaf(ee, LRELU, L));
                o[q] = EXP2(vm) * ajf;
            }
            f32x4 ov = {o[0], o[1], o[2], o[3]};
            *(f32x4*)(alphaRow + (size_t)r * 2048 + jb) = ov;   // plain store (acks at L2)
            u32 lo, hi;
            asm("v_cvt_pk_bf16_f32 %0, %1, %2" : "=v"(lo) : "v"(o[0]), "v"(o[1]));
            asm("v_cvt_pk_bf16_f32 %0, %1, %2" : "=v"(hi) : "v"(o[2]), "v"(o[3]));
            uint2 pk = {lo, hi};
            *(uint2*)&Asb[(r * 128 + sc4 * 4) ^ ((r & 7) << 3)] = pk;
        }
    };
    auto mfmaPhase = [&](const bf16x8* br, const ushort* Asb) {
        #pragma unroll
        for (int kk = 0; kk < 4; ++kk) {
            bf16x8 af = *(const bf16x8*)&Asb[(arow * 128 + kk * 32 + l4 * 8) ^ ((arow & 7) << 3)];
            acc = __builtin_amdgcn_mfma_f32_16x16x32_bf16(af, br[kk], acc, 0, 0, 0);
        }
    };

    u32 aE[4], aO[4];
    bf16x8 bE[4], bO[4];
    loadA(0, aE); loadB(0, bE);   // prologue: chunk 0 -> set E

    for (int kp = 0; kp < 8; ++kp) {
        int ke = 2 * kp, ko = 2 * kp + 1;
        // -------- even chunk: prefetch ko (loads FIRST), stage ke, 1 barrier, MFMA --------
        loadA(ko, aO); loadB(ko, bO);
        __builtin_amdgcn_sched_barrier(0);
        stage(ke, aE, As[0]);
        asm volatile("s_waitcnt lgkmcnt(0)" ::: "memory");
        __builtin_amdgcn_s_barrier();
        mfmaPhase(bE, As[0]);
        // -------- odd chunk --------
        if (ko + 1 < 16) { loadA(ko + 1, aE); loadB(ko + 1, bE); }
        __builtin_amdgcn_sched_barrier(0);
        stage(ko, aO, As[1]);
        asm volatile("s_waitcnt lgkmcnt(0)" ::: "memory");
        __builtin_amdgcn_s_barrier();
        mfmaPhase(bO, As[1]);
    }

    // epilogue: ELU + write H_new[b][node][h*32 + col]
    #pragma unroll
    for (int q = 0; q < 4; ++q) {
        int node = row0 + wr * 16 + l4 * 4 + q;
        float v = acc[q];
        v = (v > 0.f) ? v : expm1f(v);
        outH[(size_t)(b * 2048 + node) * 128 + h * 32 + wc * 16 + l15] = v;
    }
}

extern "C" void kernel_launch(void* const* d_in, const int* in_sizes, int n_in,
                              void* d_out, int out_size, void* d_ws, size_t ws_size,
                              hipStream_t stream) {
    const float* H   = (const float*)d_in[0];
    const float* adj = (const float*)d_in[1];
    const float* W   = (const float*)d_in[2];
    const float* a   = (const float*)d_in[3];

    float* outH  = (float*)d_out;
    float* alpha = outH + (size_t)4 * 2048 * 128;   // 1048576

    char* ws = (char*)d_ws;
    __hip_bfloat16* HtT = (__hip_bfloat16*)ws;                        // 2 MB
    float* src   = (float*)(ws + 2 * 1024 * 1024);                    // 128 KB
    float* dst   = src + 32768;                                       // 128 KB
    float* rowLG = dst + 32768;                                       // 128 KB
    unsigned char* adjI = (unsigned char*)(ws + 2 * 1024 * 1024 + 512 * 1024);  // 4 MB

    kA_ht<<<dim3(32, 16), 256, 0, stream>>>(H, W, a, HtT, src, dst);
    k0S<<<1024, 256, 0, stream>>>(adj, src, dst, adjI, rowLG);
    k2_fused<<<dim3(64, 16), 256, 0, stream>>>(adjI, src, dst, rowLG, HtT, alpha, outH);
}

// Round 18
// 71.252 us; speedup vs baseline: 1.1830x; 1.1830x over previous
//
#include <hip/hip_runtime.h>
#include <hip/hip_bf16.h>
#include <math.h>

// GAT: B=4, N=2048, in=128, out=32, heads=4
// outputs: H_new [4,2048,128] f32 (1048576) then alpha [4,4,2048,2048] f32 (67108864)

typedef float f32x4 __attribute__((ext_vector_type(4)));
typedef short bf16x8 __attribute__((ext_vector_type(8)));
typedef unsigned int u32;

#define LRELU 0.2f
#define LOG2E 1.44269504088896f
#define EXP2(x) __builtin_amdgcn_exp2f(x)

__device__ inline ushort f2b(float x) {
    unsigned int u = __float_as_uint(x);
    u += 0x7fffu + ((u >> 16) & 1u);   // RNE
    return (ushort)(u >> 16);
}

// ---------------- k01: grid-union of adjI-pack (4096 blocks) and Ht MFMA (512 blocks) -----
__global__ __launch_bounds__(256) void k01(const float* __restrict__ adj,
                                           unsigned char* __restrict__ adjI,
                                           const float* __restrict__ H,
                                           const float* __restrict__ W,
                                           const float* __restrict__ a,
                                           __hip_bfloat16* __restrict__ HtT,
                                           float* __restrict__ src,
                                           float* __restrict__ dst) {
    __shared__ __align__(16) ushort Wbf[32 * 128];   // k1 path: W bf16 swizzled; reused as T

    int bid = blockIdx.x;
    int t = threadIdx.x;

    if (bid >= 512) {
        // ---- k0: adjI[row][col] = (adj!=0 || col==row) ----
        int idx = (bid - 512) * 256 + t;
        int e0 = idx * 4;
        int row = e0 >> 11;
        int c0 = e0 & 2047;
        float4 v = *(const float4*)(adj + (size_t)e0);
        uchar4 o;
        o.x = (v.x != 0.f || c0     == row) ? 1 : 0;
        o.y = (v.y != 0.f || c0 + 1 == row) ? 1 : 0;
        o.z = (v.z != 0.f || c0 + 2 == row) ? 1 : 0;
        o.w = (v.w != 0.f || c0 + 3 == row) ? 1 : 0;
        *(uchar4*)(adjI + (size_t)e0) = o;
        return;
    }

    // ---- k1: Ht^T = W^T @ H^T (MFMA), + src/dst dots ----
    int ntile = bid & 31;
    int bh = bid >> 5;
    int b = bh >> 2, h = bh & 3;
    int lane = t & 63, w = t >> 6;
    int l15 = lane & 15, l4 = lane >> 4;

    #pragma unroll
    for (int u = 0; u < 16; ++u) {
        int idx = u * 256 + t;
        int i = idx >> 5, f = idx & 31;
        Wbf[(f * 128 + i) ^ ((f & 7) << 3)] = f2b(W[h * 4096 + idx]);
    }
    __syncthreads();

    int n = ntile * 64 + w * 16 + l15;
    const float* hrow = H + ((size_t)(b * 2048) + n) * 128;

    f32x4 acc0 = {0.f, 0.f, 0.f, 0.f};   // f rows 0-15
    f32x4 acc1 = {0.f, 0.f, 0.f, 0.f};   // f rows 16-31
    #pragma unroll
    for (int kc = 0; kc < 4; ++kc) {
        int k0 = kc * 32 + l4 * 8;
        float4 h0 = *(const float4*)(hrow + k0);
        float4 h1 = *(const float4*)(hrow + k0 + 4);
        union { u32 u[4]; bf16x8 v; } bu;
        asm("v_cvt_pk_bf16_f32 %0, %1, %2" : "=v"(bu.u[0]) : "v"(h0.x), "v"(h0.y));
        asm("v_cvt_pk_bf16_f32 %0, %1, %2" : "=v"(bu.u[1]) : "v"(h0.z), "v"(h0.w));
        asm("v_cvt_pk_bf16_f32 %0, %1, %2" : "=v"(bu.u[2]) : "v"(h1.x), "v"(h1.y));
        asm("v_cvt_pk_bf16_f32 %0, %1, %2" : "=v"(bu.u[3]) : "v"(h1.z), "v"(h1.w));
        bf16x8 bfrag = bu.v;
        bf16x8 af0 = *(const bf16x8*)&Wbf[(l15 * 128 + kc * 32 + l4 * 8) ^ ((l15 & 7) << 3)];
        bf16x8 af1 = *(const bf16x8*)&Wbf[((16 + l15) * 128 + kc * 32 + l4 * 8) ^ (((16 + l15) & 7) << 3)];
        acc0 = __builtin_amdgcn_mfma_f32_16x16x32_bf16(af0, bfrag, acc0, 0, 0, 0);
        acc1 = __builtin_amdgcn_mfma_f32_16x16x32_bf16(af1, bfrag, acc1, 0, 0, 0);
    }

    // src/dst dots from accumulators
    float sv = 0.f, dvv = 0.f;
    #pragma unroll
    for (int r = 0; r < 4; ++r) {
        int f0 = l4 * 4 + r;
        sv  += acc0[r] * a[h * 64 + f0]      + acc1[r] * a[h * 64 + 16 + f0];
        dvv += acc0[r] * a[h * 64 + 32 + f0] + acc1[r] * a[h * 64 + 48 + f0];
    }
    sv  += __shfl_xor(sv, 16);  sv  += __shfl_xor(sv, 32);
    dvv += __shfl_xor(dvv, 16); dvv += __shfl_xor(dvv, 32);
    if (l4 == 0) { src[bh * 2048 + n] = sv; dst[bh * 2048 + n] = dvv; }

    // HtT via LDS transpose (reuse Wbf as T[32 f][64 n]) for coalesced 16B stores
    __syncthreads();
    ushort* T = Wbf;
    int nl = w * 16 + l15;
    #pragma unroll
    for (int r = 0; r < 4; ++r) {
        int f0 = l4 * 4 + r;
        T[f0 * 64 + nl]        = f2b(acc0[r]);
        T[(16 + f0) * 64 + nl] = f2b(acc1[r]);
    }
    __syncthreads();
    {
        int f = t >> 3, n8 = (t & 7) * 8;
        uint4 v = *(const uint4*)&T[f * 64 + n8];
        *(uint4*)((ushort*)HtT + (size_t)(bh * 32 + f) * 2048 + ntile * 64 + n8) = v;
    }
}

// ---------------- fused: softmax -> alpha (plain store) -> MFMA -> ELU -> H_new ------------
// grid (64 mtiles of 32 rows, 16 bh), block 256 (4 waves). 4 blocks/CU (VGPR cap 128).
// As double-buffered: ONE lgkm-only barrier per K-chunk; loads always issued before stores.
__global__ __launch_bounds__(256, 4) void k2_fused(const unsigned char* __restrict__ adjI,
                                                   const float* __restrict__ src,
                                                   const float* __restrict__ dst,
                                                   const __hip_bfloat16* __restrict__ HtT,
                                                   float* __restrict__ alpha,
                                                   float* __restrict__ outH) {
    __shared__ float dstS[2048];                      // 8 KB (pre-scaled by LOG2E)
    __shared__ float rowL[32], rowSrcS[32];
    __shared__ __align__(16) ushort As[2][32 * 128];  // 16 KB dbuf, XOR-swizzled

    int t = threadIdx.x;
    int mtile = blockIdx.x;   // 64
    int bh    = blockIdx.y;   // 16
    int lane = t & 63, w = t >> 6;
    int b = bh >> 2, h = bh & 3;
    int row0 = mtile * 32;

    const float4* dst4g = (const float4*)(dst + bh * 2048);
    #pragma unroll
    for (int u = 0; u < 2; ++u) {
        float4 v = dst4g[u * 256 + t];
        v.x *= LOG2E; v.y *= LOG2E; v.z *= LOG2E; v.w *= LOG2E;
        *(float4*)&dstS[(u * 256 + t) * 4] = v;
    }
    if (t < 32) rowSrcS[t] = src[bh * 2048 + row0 + t] * LOG2E;
    __syncthreads();

    // ---- pass A: per-row S = sum_j adjI * exp2(leaky(ee)); store L = -log2(S) ----
    for (int rr = 0; rr < 8; ++rr) {
        int r = w * 8 + rr;
        int gr = row0 + r;
        float sn = rowSrcS[r];
        const uint4* a16 = (const uint4*)(adjI + (size_t)gr * 2048);
        float S = 0.f;
        #pragma unroll
        for (int u = 0; u < 2; ++u) {
            uint4 ab = a16[u * 64 + lane];
            int jb = (u * 64 + lane) * 16;
            u32 words[4] = {ab.x, ab.y, ab.z, ab.w};
            #pragma unroll
            for (int wq = 0; wq < 4; ++wq) {
                float4 dv = *(const float4*)&dstS[jb + wq * 4];
                float dj[4] = {dv.x, dv.y, dv.z, dv.w};
                #pragma unroll
                for (int q = 0; q < 4; ++q) {
                    float ajf = (float)((words[wq] >> (8 * q)) & 0xffu);
                    float ee = sn + dj[q];
                    float vm = fmaxf(ee, LRELU * ee);
                    S = fmaf(EXP2(vm), ajf, S);
                }
            }
        }
        #pragma unroll
        for (int off = 32; off; off >>= 1) S += __shfl_xor(S, off);
        if (lane == 0) rowL[r] = -__log2f(S);
    }
    __syncthreads();

    // ---- pass B ----
    f32x4 acc = {0.f, 0.f, 0.f, 0.f};
    int wr = w >> 1, wc = w & 1;
    int l15 = lane & 15, l4 = lane >> 4;
    int arow = wr * 16 + l15;
    const ushort* Bfp = (const ushort*)HtT + (size_t)(bh * 32 + wc * 16 + l15) * 2048 + l4 * 8;
    float* alphaRow = alpha + (size_t)(bh * 2048 + row0) * 2048;

    int sr = t >> 5;            // rows sr, sr+8, sr+16, sr+24
    int sc4 = t & 31;

    float snR[4], LR[4];
    #pragma unroll
    for (int u = 0; u < 4; ++u) { snR[u] = rowSrcS[sr + u * 8]; LR[u] = rowL[sr + u * 8]; }

    auto loadA = [&](int k, u32* ar) {
        #pragma unroll
        for (int u = 0; u < 4; ++u)
            ar[u] = *(const u32*)(adjI + (size_t)(row0 + sr + u * 8) * 2048 + k * 128 + sc4 * 4);
    };
    auto loadB = [&](int k, bf16x8* br) {
        #pragma unroll
        for (int kk = 0; kk < 4; ++kk)
            br[kk] = *(const bf16x8*)(Bfp + (size_t)k * 128 + kk * 32);
    };
    auto stage = [&](int k, const u32* ar, ushort* Asb) {
        int jb = k * 128 + sc4 * 4;
        float4 dv = *(const float4*)&dstS[jb];
        float dj[4] = {dv.x, dv.y, dv.z, dv.w};
        #pragma unroll
        for (int u = 0; u < 4; ++u) {
            int r = sr + u * 8;
            float sn = snR[u], L = LR[u];
            u32 ab = ar[u];
            float o[4];
            #pragma unroll
            for (int q = 0; q < 4; ++q) {
                float ajf = (float)((ab >> (8 * q)) & 0xffu);
                float ee = sn + dj[q];
                float vm = fmaxf(ee + L, fmaf(ee, LRELU, L));
                o[q] = EXP2(vm) * ajf;
            }
            f32x4 ov = {o[0], o[1], o[2], o[3]};
            *(f32x4*)(alphaRow + (size_t)r * 2048 + jb) = ov;   // plain store (acks at L2)
            u32 lo, hi;
            asm("v_cvt_pk_bf16_f32 %0, %1, %2" : "=v"(lo) : "v"(o[0]), "v"(o[1]));
            asm("v_cvt_pk_bf16_f32 %0, %1, %2" : "=v"(hi) : "v"(o[2]), "v"(o[3]));
            uint2 pk = {lo, hi};
            *(uint2*)&Asb[(r * 128 + sc4 * 4) ^ ((r & 7) << 3)] = pk;
        }
    };
    auto mfmaPhase = [&](const bf16x8* br, const ushort* Asb) {
        #pragma unroll
        for (int kk = 0; kk < 4; ++kk) {
            bf16x8 af = *(const bf16x8*)&Asb[(arow * 128 + kk * 32 + l4 * 8) ^ ((arow & 7) << 3)];
            acc = __builtin_amdgcn_mfma_f32_16x16x32_bf16(af, br[kk], acc, 0, 0, 0);
        }
    };

    u32 aE[4], aO[4];
    bf16x8 bE[4], bO[4];
    loadA(0, aE); loadB(0, bE);   // prologue: chunk 0 -> set E

    for (int kp = 0; kp < 8; ++kp) {
        int ke = 2 * kp, ko = 2 * kp + 1;
        // -------- even chunk: prefetch ko (loads FIRST), stage ke, 1 barrier, MFMA --------
        loadA(ko, aO); loadB(ko, bO);
        __builtin_amdgcn_sched_barrier(0);
        stage(ke, aE, As[0]);
        asm volatile("s_waitcnt lgkmcnt(0)" ::: "memory");
        __builtin_amdgcn_s_barrier();
        mfmaPhase(bE, As[0]);
        // -------- odd chunk --------
        if (ko + 1 < 16) { loadA(ko + 1, aE); loadB(ko + 1, bE); }
        __builtin_amdgcn_sched_barrier(0);
        stage(ko, aO, As[1]);
        asm volatile("s_waitcnt lgkmcnt(0)" ::: "memory");
        __builtin_amdgcn_s_barrier();
        mfmaPhase(bO, As[1]);
    }

    // epilogue: ELU + write H_new[b][node][h*32 + col]
    #pragma unroll
    for (int q = 0; q < 4; ++q) {
        int node = row0 + wr * 16 + l4 * 4 + q;
        float v = acc[q];
        v = (v > 0.f) ? v : expm1f(v);
        outH[(size_t)(b * 2048 + node) * 128 + h * 32 + wc * 16 + l15] = v;
    }
}

extern "C" void kernel_launch(void* const* d_in, const int* in_sizes, int n_in,
                              void* d_out, int out_size, void* d_ws, size_t ws_size,
                              hipStream_t stream) {
    const float* H   = (const float*)d_in[0];
    const float* adj = (const float*)d_in[1];
    const float* W   = (const float*)d_in[2];
    const float* a   = (const float*)d_in[3];

    float* outH  = (float*)d_out;
    float* alpha = outH + (size_t)4 * 2048 * 128;   // 1048576

    char* ws = (char*)d_ws;
    __hip_bfloat16* HtT = (__hip_bfloat16*)ws;                    // 2 MB
    float* src = (float*)(ws + 2 * 1024 * 1024);                  // 128 KB
    float* dst = src + 32768;                                     // 128 KB
    unsigned char* adjI = (unsigned char*)(ws + 2 * 1024 * 1024 + 256 * 1024);  // 4 MB

    k01<<<4608, 256, 0, stream>>>(adj, adjI, H, W, a, HtT, src, dst);
    k2_fused<<<dim3(64, 16), 256, 0, stream>>>(adjI, src, dst, HtT, alpha, outH);
}